// Round 1
// baseline (1989.462 us; speedup 1.0000x reference)
//
#include <hip/hip_runtime.h>
#include <stdint.h>

#define L48   48
#define NLOC  2304      // 48*48
#define C3CH  256
#define KDIM  2304      // 256*9
#define BATCH 4

// ---------------- norms: one wave per patch location ----------------
__global__ __launch_bounds__(256) void norm_kernel(const float* __restrict__ img,
                                                   float* __restrict__ inv_norm)
{
    int wid  = (blockIdx.x * 256 + threadIdx.x) >> 6;
    int lane = threadIdx.x & 63;
    if (wid >= BATCH * NLOC) return;
    int b = wid / NLOC;
    int m = wid - b * NLOC;
    int y = m / L48, x = m - y * L48;
    const float* base = img + (size_t)b * C3CH * NLOC;
    float acc = 0.f;
    for (int e = lane; e < KDIM; e += 64) {
        int c = e / 9;
        int r = e - c * 9;
        int yy = y + r / 3 - 1;
        int xx = x + (r % 3) - 1;
        float v = 0.f;
        if ((unsigned)yy < 48u && (unsigned)xx < 48u)
            v = base[c * NLOC + yy * L48 + xx];
        acc += v * v;
    }
    #pragma unroll
    for (int off = 32; off >= 1; off >>= 1)
        acc += __shfl_xor(acc, off, 64);
    if (lane == 0) {
        float n = fmaxf(sqrtf(acc), 1e-12f);
        inv_norm[wid] = 1.f / n;
    }
}

// ------------- search: fp32 GEMM 128x128 tile, fused argmax over l -------------
__global__ __launch_bounds__(256) void search_kernel(const float* __restrict__ refsr,
                                                     const float* __restrict__ lrsr,
                                                     const float* __restrict__ nr_inv,
                                                     unsigned long long* __restrict__ packed)
{
    __shared__ float As[8][128];
    __shared__ float Bs[8][128];
    __shared__ float redv[16][128];
    __shared__ int   redi[16][128];

    const int b  = blockIdx.z;
    const int l0 = blockIdx.y * 128;
    const int m0 = blockIdx.x * 128;
    const int tid = threadIdx.x;
    const int ty = tid >> 4, tx = tid & 15;
    const int li  = tid & 127;
    const int kkb = tid >> 7;          // 0 or 1

    const int ly = (l0 + li) / L48, lx = (l0 + li) - ly * L48;
    const int my = (m0 + li) / L48, mx = (m0 + li) - my * L48;
    const float* Abase = refsr + (size_t)b * C3CH * NLOC;
    const float* Bbase = lrsr  + (size_t)b * C3CH * NLOC;

    float acc[8][8];
    #pragma unroll
    for (int r = 0; r < 8; ++r)
        #pragma unroll
        for (int c = 0; c < 8; ++c) acc[r][c] = 0.f;

    for (int o = 0; o < 9; ++o) {
        const int ki = o / 3 - 1, kj = o % 3 - 1;
        const int ay = ly + ki, ax = lx + kj;
        const int by = my + ki, bx = mx + kj;
        const bool av = ((unsigned)ay < 48u) && ((unsigned)ax < 48u);
        const bool bv = ((unsigned)by < 48u) && ((unsigned)bx < 48u);
        const float* Ap = Abase + ay * L48 + ax;
        const float* Bp = Bbase + by * L48 + bx;

        for (int s = 0; s < 32; ++s) {
            __syncthreads();
            #pragma unroll
            for (int j = 0; j < 4; ++j) {
                int kk = kkb + 2 * j;
                int c  = s * 8 + kk;
                As[kk][li] = av ? Ap[c * NLOC] : 0.f;
                Bs[kk][li] = bv ? Bp[c * NLOC] : 0.f;
            }
            __syncthreads();
            #pragma unroll
            for (int kk = 0; kk < 8; ++kk) {
                float a[8], bb[8];
                #pragma unroll
                for (int r = 0; r < 8; ++r) a[r] = As[kk][ty * 8 + r];
                #pragma unroll
                for (int c = 0; c < 8; ++c) bb[c] = Bs[kk][tx * 8 + c];
                #pragma unroll
                for (int r = 0; r < 8; ++r)
                    #pragma unroll
                    for (int c = 0; c < 8; ++c)
                        acc[r][c] = fmaf(a[r], bb[c], acc[r][c]);
            }
        }
    }

    // row scale by 1/||ref patch||, per-thread column max (ascending l => first-max-wins)
    float rinv[8];
    #pragma unroll
    for (int r = 0; r < 8; ++r) rinv[r] = nr_inv[b * NLOC + l0 + ty * 8 + r];

    #pragma unroll
    for (int c = 0; c < 8; ++c) {
        float best = acc[0][c] * rinv[0];
        int   bi   = l0 + ty * 8;
        #pragma unroll
        for (int r = 1; r < 8; ++r) {
            float v = acc[r][c] * rinv[r];
            if (v > best) { best = v; bi = l0 + ty * 8 + r; }
        }
        redv[ty][tx * 8 + c] = best;
        redi[ty][tx * 8 + c] = bi;
    }
    __syncthreads();
    if (tid < 128) {
        float best = redv[0][tid];
        int   bi   = redi[0][tid];
        #pragma unroll
        for (int r = 1; r < 16; ++r) {
            float v  = redv[r][tid];
            int   i2 = redi[r][tid];
            if (v > best || (v == best && i2 < bi)) { best = v; bi = i2; }
        }
        unsigned int sv = __float_as_uint(best);
        sv = (sv & 0x80000000u) ? ~sv : (sv | 0x80000000u);
        unsigned long long p = ((unsigned long long)sv << 32)
                             | (unsigned long long)(0xFFFFFFFFu - (unsigned)bi);
        atomicMax(packed + b * NLOC + m0 + tid, p);
    }
}

// ---------------- finalize: unpack S and argmax ----------------
__global__ __launch_bounds__(256) void finalize_kernel(const unsigned long long* __restrict__ packed,
                                                       const float* __restrict__ nl_inv,
                                                       float* __restrict__ S,
                                                       int* __restrict__ Rarg)
{
    int i = blockIdx.x * 256 + threadIdx.x;
    if (i >= BATCH * NLOC) return;
    unsigned long long p = packed[i];
    unsigned int sv   = (unsigned int)(p >> 32);
    unsigned int bits = (sv & 0x80000000u) ? (sv & 0x7FFFFFFFu) : ~sv;
    float val = __uint_as_float(bits);
    int   idx = (int)(0xFFFFFFFFu - (unsigned int)(p & 0xFFFFFFFFu));
    S[i]    = val * nl_inv[i];
    Rarg[i] = idx;
}

// ------------- transfer: fused gather + fold (no im2col materialization) -------------
// out[b,c,y,x] = (1/9) * sum over covering patch positions (py,px) of
//               ref[b, c, qy*S + (y+P - py*S) - P, qx*S + (x+P - px*S) - P]   (0 if OOB)
template<int C, int H, int K, int S, int P>
__global__ __launch_bounds__(256) void transfer_kernel(const float* __restrict__ ref,
                                                       const int* __restrict__ Rarg,
                                                       float* __restrict__ out)
{
    int idx = blockIdx.x * 256 + threadIdx.x;
    if (idx >= BATCH * C * H * H) return;
    int x = idx % H;
    int y = (idx / H) % H;
    int c = (idx / (H * H)) % C;
    int b = idx / (H * H * C);
    int Y = y + P, X = x + P;
    int ylo = Y - K + 1; ylo = (ylo > 0) ? (ylo + S - 1) / S : 0;
    int yhi = Y / S; if (yhi > 47) yhi = 47;
    int xlo = X - K + 1; xlo = (xlo > 0) ? (xlo + S - 1) / S : 0;
    int xhi = X / S; if (xhi > 47) xhi = 47;
    const float* rbase = ref + ((size_t)b * C + c) * H * H;
    const int*   abase = Rarg + b * NLOC;
    float acc = 0.f;
    for (int py = ylo; py <= yhi; ++py) {
        int ki = Y - py * S;
        for (int px = xlo; px <= xhi; ++px) {
            int kj = X - px * S;
            int q  = abase[py * L48 + px];
            int qy = q / L48, qx = q - qy * L48;
            int row = qy * S + ki - P;
            int col = qx * S + kj - P;
            if ((unsigned)row < (unsigned)H && (unsigned)col < (unsigned)H)
                acc += rbase[row * H + col];
        }
    }
    out[idx] = acc * (1.f / 9.f);
}

extern "C" void kernel_launch(void* const* d_in, const int* in_sizes, int n_in,
                              void* d_out, int out_size, void* d_ws, size_t ws_size,
                              hipStream_t stream)
{
    const float* lrsr  = (const float*)d_in[0];
    const float* refsr = (const float*)d_in[1];
    const float* ref1  = (const float*)d_in[2];
    const float* ref2  = (const float*)d_in[3];
    const float* ref3  = (const float*)d_in[4];

    float* S_out  = (float*)d_out;                   // B*1*48*48   = 9216
    float* T3_out = S_out  + BATCH * NLOC;           // B*256*48*48 = 2359296
    float* T2_out = T3_out + BATCH * 256 * 48 * 48;  // B*128*96*96 = 4718592
    float* T1_out = T2_out + BATCH * 128 * 96 * 96;  // B*64*192*192= 9437184

    char* ws = (char*)d_ws;
    unsigned long long* packed = (unsigned long long*)ws;       // 9216*8 B
    float* nr_inv = (float*)(ws + BATCH * NLOC * 8);
    float* nl_inv = nr_inv + BATCH * NLOC;
    int*   Rarg   = (int*)(nl_inv + BATCH * NLOC);

    hipMemsetAsync(packed, 0, BATCH * NLOC * sizeof(unsigned long long), stream);
    norm_kernel<<<dim3(BATCH * NLOC / 4), 256, 0, stream>>>(refsr, nr_inv);
    norm_kernel<<<dim3(BATCH * NLOC / 4), 256, 0, stream>>>(lrsr,  nl_inv);

    search_kernel<<<dim3(18, 18, BATCH), 256, 0, stream>>>(refsr, lrsr, nr_inv, packed);

    finalize_kernel<<<dim3(36), 256, 0, stream>>>(packed, nl_inv, S_out, Rarg);

    transfer_kernel<256,  48,  3, 1, 1><<<dim3(BATCH*256*48*48   / 256), 256, 0, stream>>>(ref3, Rarg, T3_out);
    transfer_kernel<128,  96,  6, 2, 2><<<dim3(BATCH*128*96*96   / 256), 256, 0, stream>>>(ref2, Rarg, T2_out);
    transfer_kernel< 64, 192, 12, 4, 4><<<dim3(BATCH*64*192*192  / 256), 256, 0, stream>>>(ref1, Rarg, T1_out);
}

// Round 2
// 826.333 us; speedup vs baseline: 2.4076x; 2.4076x over previous
//
#include <hip/hip_runtime.h>
#include <stdint.h>

#define L48   48
#define NLOC  2304      // 48*48
#define C3CH  256
#define KDIM  2304      // 256*9
#define BATCH 4
#define PADLOC 2400     // 50 rows * 48

typedef _Float16 half8 __attribute__((ext_vector_type(8)));
typedef float    floatx4 __attribute__((ext_vector_type(4)));
typedef unsigned short ushort8v __attribute__((ext_vector_type(8)));

union H16 { _Float16 f; unsigned short u; };

// ---------------- norms: one wave per patch location (unchanged) ----------------
__global__ __launch_bounds__(256) void norm_kernel(const float* __restrict__ img,
                                                   float* __restrict__ inv_norm)
{
    int wid  = (blockIdx.x * 256 + threadIdx.x) >> 6;
    int lane = threadIdx.x & 63;
    if (wid >= BATCH * NLOC) return;
    int b = wid / NLOC;
    int m = wid - b * NLOC;
    int y = m / L48, x = m - y * L48;
    const float* base = img + (size_t)b * C3CH * NLOC;
    float acc = 0.f;
    for (int e = lane; e < KDIM; e += 64) {
        int c = e / 9;
        int r = e - c * 9;
        int yy = y + r / 3 - 1;
        int xx = x + (r % 3) - 1;
        float v = 0.f;
        if ((unsigned)yy < 48u && (unsigned)xx < 48u)
            v = base[c * NLOC + yy * L48 + xx];
        acc += v * v;
    }
    #pragma unroll
    for (int off = 32; off >= 1; off >>= 1)
        acc += __shfl_xor(acc, off, 64);
    if (lane == 0) {
        float n = fmaxf(sqrtf(acc), 1e-12f);
        inv_norm[wid] = 1.f / n;
    }
}

// ---------------- prep: fp32 image -> channel-last padded split-fp16 ----------------
// out[part][oxIdx][b][loc' = yy*48+x][c], yy in [0,50) meaning y=yy-1, value = img[c][y][x+ox-1] (0 OOB)
__global__ __launch_bounds__(256) void prep_kernel(const float* __restrict__ img,
                                                   unsigned short* __restrict__ out_hi,
                                                   unsigned short* __restrict__ out_lo)
{
    __shared__ unsigned short hi[256 * 50];
    __shared__ unsigned short lo[256 * 50];
    int bid = blockIdx.x;
    int oxIdx = bid / 200;
    int rem   = bid % 200;
    int b     = rem / 50;
    int yy    = rem % 50;
    int kj = oxIdx - 1;
    int y  = yy - 1;
    int t = threadIdx.x;
    bool yok = (unsigned)y < 48u;
    const float* ibase = img + (size_t)b * C3CH * NLOC;
    for (int flat = t; flat < 256 * 48; flat += 256) {
        int c = flat / 48;
        int x = flat - c * 48;
        int xs = x + kj;
        float v = 0.f;
        if (yok && (unsigned)xs < 48u)
            v = ibase[c * NLOC + y * L48 + xs];
        H16 h, l;
        h.f = (_Float16)v;
        float rvv = (v - (float)h.f) * 2048.0f;
        l.f = (_Float16)rvv;
        hi[c * 50 + x] = h.u;
        lo[c * 50 + x] = l.u;
    }
    __syncthreads();
    size_t obase = ((size_t)(oxIdx * 4 + b) * PADLOC + (size_t)yy * 48) * 256;
    for (int flat = t; flat < 256 * 48; flat += 256) {
        int c = flat & 255;
        int x = flat >> 8;
        out_hi[obase + (size_t)x * 256 + c] = hi[c * 50 + x];
        out_lo[obase + (size_t)x * 256 + c] = lo[c * 50 + x];
    }
}

// ---------------- search: fp16 hi/lo split MFMA GEMM, fused argmax ----------------
__global__ __launch_bounds__(256, 2) void search_mfma(const unsigned short* __restrict__ At_hi,
                                                      const unsigned short* __restrict__ At_lo,
                                                      const unsigned short* __restrict__ Bt_hi,
                                                      const unsigned short* __restrict__ Bt_lo,
                                                      const float* __restrict__ nr_inv,
                                                      unsigned long long* __restrict__ packed)
{
    __shared__ unsigned short lds[4 * 5120];   // Ah, Al, Bh, Bl : each 128 rows x 40 (pad) fp16
    unsigned short* Ah = lds;
    unsigned short* Al = lds + 5120;
    unsigned short* Bh = lds + 10240;
    unsigned short* Bl = lds + 15360;

    const int tid = threadIdx.x;
    const int b  = blockIdx.z;
    const int l0 = blockIdx.y * 128;
    const int m0 = blockIdx.x * 128;

    const int lane = tid & 63;
    const int wr = tid >> 7;          // wave row 0..1
    const int wc = (tid >> 6) & 1;    // wave col 0..1
    const int mrow = lane & 15;
    const int koff = (lane >> 4) * 8; // fp16 units

    const int srow0 = tid >> 2;            // staging row 0..63
    const int sgrp  = (tid & 3) * 8;       // staging 8-ch group offset (fp16 units)

    floatx4 acc1[4][4];
    floatx4 acc2[4][4];
    #pragma unroll
    for (int i = 0; i < 4; ++i)
        #pragma unroll
        for (int j = 0; j < 4; ++j) { acc1[i][j] = (floatx4)0.f; acc2[i][j] = (floatx4)0.f; }

    for (int o = 0; o < 9; ++o) {
        const int ki = o / 3 - 1;
        const int ox = o % 3;
        const size_t locA = (size_t)(ox * 4 + b) * PADLOC + l0 + 48 * (1 + ki);
        const size_t locB = (size_t)(ox * 4 + b) * PADLOC + m0 + 48 * (1 + ki);
        const unsigned short* pAh = At_hi + locA * 256;
        const unsigned short* pAl = At_lo + locA * 256;
        const unsigned short* pBh = Bt_hi + locB * 256;
        const unsigned short* pBl = Bt_lo + locB * 256;

        for (int cc = 0; cc < 8; ++cc) {
            const int c0 = cc * 32;
            #pragma unroll
            for (int j = 0; j < 2; ++j) {
                int row = srow0 + 64 * j;
                size_t g = (size_t)row * 256 + c0 + sgrp;
                int s = row * 40 + sgrp;
                *(ushort8v*)(Ah + s) = *(const ushort8v*)(pAh + g);
                *(ushort8v*)(Al + s) = *(const ushort8v*)(pAl + g);
                *(ushort8v*)(Bh + s) = *(const ushort8v*)(pBh + g);
                *(ushort8v*)(Bl + s) = *(const ushort8v*)(pBl + g);
            }
            __syncthreads();

            half8 ahf[4], alf[4];
            #pragma unroll
            for (int fi = 0; fi < 4; ++fi) {
                int r = wr * 64 + fi * 16 + mrow;
                ahf[fi] = *(const half8*)((const _Float16*)Ah + r * 40 + koff);
                alf[fi] = *(const half8*)((const _Float16*)Al + r * 40 + koff);
            }
            #pragma unroll
            for (int fj = 0; fj < 4; ++fj) {
                int r = wc * 64 + fj * 16 + mrow;
                half8 bhf = *(const half8*)((const _Float16*)Bh + r * 40 + koff);
                half8 blf = *(const half8*)((const _Float16*)Bl + r * 40 + koff);
                #pragma unroll
                for (int fi = 0; fi < 4; ++fi) {
                    acc1[fi][fj] = __builtin_amdgcn_mfma_f32_16x16x32_f16(ahf[fi], bhf, acc1[fi][fj], 0, 0, 0);
                    acc2[fi][fj] = __builtin_amdgcn_mfma_f32_16x16x32_f16(ahf[fi], blf, acc2[fi][fj], 0, 0, 0);
                    acc2[fi][fj] = __builtin_amdgcn_mfma_f32_16x16x32_f16(alf[fi], bhf, acc2[fi][fj], 0, 0, 0);
                }
            }
            __syncthreads();
        }
    }

    // ---- epilogue: row-normalize, per-column argmax over l within block ----
    float* redv = (float*)lds;               // [8][128]
    int*   redi = (int*)(redv + 8 * 128);    // [8][128]

    const float inv2048 = 1.0f / 2048.0f;
    float bestv[4];
    int   besti[4];
    #pragma unroll
    for (int fj = 0; fj < 4; ++fj) { bestv[fj] = -1e30f; besti[fj] = 0; }

    #pragma unroll
    for (int fi = 0; fi < 4; ++fi) {
        int rowbase = l0 + wr * 64 + fi * 16 + (lane >> 4) * 4;
        #pragma unroll
        for (int r = 0; r < 4; ++r) {
            float rinv = nr_inv[b * NLOC + rowbase + r];
            #pragma unroll
            for (int fj = 0; fj < 4; ++fj) {
                float v = (acc1[fi][fj][r] + acc2[fi][fj][r] * inv2048) * rinv;
                if (v > bestv[fj]) { bestv[fj] = v; besti[fj] = rowbase + r; }
            }
        }
    }

    int cand = wr * 4 + (lane >> 4);   // 0..7
    #pragma unroll
    for (int fj = 0; fj < 4; ++fj) {
        int col = wc * 64 + fj * 16 + mrow;
        redv[cand * 128 + col] = bestv[fj];
        redi[cand * 128 + col] = besti[fj];
    }
    __syncthreads();
    if (tid < 128) {
        float best = redv[tid];
        int   bi   = redi[tid];
        #pragma unroll
        for (int c = 1; c < 8; ++c) {
            float v  = redv[c * 128 + tid];
            int   i2 = redi[c * 128 + tid];
            if (v > best || (v == best && i2 < bi)) { best = v; bi = i2; }
        }
        unsigned int sv = __float_as_uint(best);
        sv = (sv & 0x80000000u) ? ~sv : (sv | 0x80000000u);
        unsigned long long p = ((unsigned long long)sv << 32)
                             | (unsigned long long)(0xFFFFFFFFu - (unsigned)bi);
        atomicMax(packed + b * NLOC + m0 + tid, p);
    }
}

// ---------------- finalize: unpack S and argmax (unchanged) ----------------
__global__ __launch_bounds__(256) void finalize_kernel(const unsigned long long* __restrict__ packed,
                                                       const float* __restrict__ nl_inv,
                                                       float* __restrict__ S,
                                                       int* __restrict__ Rarg)
{
    int i = blockIdx.x * 256 + threadIdx.x;
    if (i >= BATCH * NLOC) return;
    unsigned long long p = packed[i];
    unsigned int sv   = (unsigned int)(p >> 32);
    unsigned int bits = (sv & 0x80000000u) ? (sv & 0x7FFFFFFFu) : ~sv;
    float val = __uint_as_float(bits);
    int   idx = (int)(0xFFFFFFFFu - (unsigned int)(p & 0xFFFFFFFFu));
    S[i]    = val * nl_inv[i];
    Rarg[i] = idx;
}

// ------------- transfer: fused gather + fold (unchanged) -------------
template<int C, int H, int K, int S, int P>
__global__ __launch_bounds__(256) void transfer_kernel(const float* __restrict__ ref,
                                                       const int* __restrict__ Rarg,
                                                       float* __restrict__ out)
{
    int idx = blockIdx.x * 256 + threadIdx.x;
    if (idx >= BATCH * C * H * H) return;
    int x = idx % H;
    int y = (idx / H) % H;
    int c = (idx / (H * H)) % C;
    int b = idx / (H * H * C);
    int Y = y + P, X = x + P;
    int ylo = Y - K + 1; ylo = (ylo > 0) ? (ylo + S - 1) / S : 0;
    int yhi = Y / S; if (yhi > 47) yhi = 47;
    int xlo = X - K + 1; xlo = (xlo > 0) ? (xlo + S - 1) / S : 0;
    int xhi = X / S; if (xhi > 47) xhi = 47;
    const float* rbase = ref + ((size_t)b * C + c) * H * H;
    const int*   abase = Rarg + b * NLOC;
    float acc = 0.f;
    for (int py = ylo; py <= yhi; ++py) {
        int ki = Y - py * S;
        for (int px = xlo; px <= xhi; ++px) {
            int kj = X - px * S;
            int q  = abase[py * L48 + px];
            int qy = q / L48, qx = q - qy * L48;
            int row = qy * S + ki - P;
            int col = qx * S + kj - P;
            if ((unsigned)row < (unsigned)H && (unsigned)col < (unsigned)H)
                acc += rbase[row * H + col];
        }
    }
    out[idx] = acc * (1.f / 9.f);
}

extern "C" void kernel_launch(void* const* d_in, const int* in_sizes, int n_in,
                              void* d_out, int out_size, void* d_ws, size_t ws_size,
                              hipStream_t stream)
{
    const float* lrsr  = (const float*)d_in[0];
    const float* refsr = (const float*)d_in[1];
    const float* ref1  = (const float*)d_in[2];
    const float* ref2  = (const float*)d_in[3];
    const float* ref3  = (const float*)d_in[4];

    float* S_out  = (float*)d_out;                   // 9216
    float* T3_out = S_out  + BATCH * NLOC;           // 2359296
    float* T2_out = T3_out + BATCH * 256 * 48 * 48;  // 4718592
    float* T1_out = T2_out + BATCH * 128 * 96 * 96;  // 9437184

    char* ws = (char*)d_ws;
    unsigned long long* packed = (unsigned long long*)ws;         // 73728 B
    float* nr_inv = (float*)(ws + 73728);                         // 36864 B
    float* nl_inv = (float*)(ws + 110592);                        // 36864 B
    int*   Rarg   = (int*)(ws + 147456);                          // 36864 B
    const size_t TSZ = (size_t)3 * BATCH * PADLOC * 256;          // 7372800 elements
    unsigned short* A_hi = (unsigned short*)(ws + 184320);
    unsigned short* A_lo = A_hi + TSZ;
    unsigned short* B_hi = A_lo + TSZ;
    unsigned short* B_lo = B_hi + TSZ;

    hipMemsetAsync(packed, 0, BATCH * NLOC * sizeof(unsigned long long), stream);
    norm_kernel<<<dim3(BATCH * NLOC / 4), 256, 0, stream>>>(refsr, nr_inv);
    norm_kernel<<<dim3(BATCH * NLOC / 4), 256, 0, stream>>>(lrsr,  nl_inv);
    prep_kernel<<<dim3(600), 256, 0, stream>>>(refsr, A_hi, A_lo);
    prep_kernel<<<dim3(600), 256, 0, stream>>>(lrsr,  B_hi, B_lo);

    search_mfma<<<dim3(18, 18, BATCH), 256, 0, stream>>>(A_hi, A_lo, B_hi, B_lo, nr_inv, packed);

    finalize_kernel<<<dim3(36), 256, 0, stream>>>(packed, nl_inv, S_out, Rarg);

    transfer_kernel<256,  48,  3, 1, 1><<<dim3(BATCH*256*48*48   / 256), 256, 0, stream>>>(ref3, Rarg, T3_out);
    transfer_kernel<128,  96,  6, 2, 2><<<dim3(BATCH*128*96*96   / 256), 256, 0, stream>>>(ref2, Rarg, T2_out);
    transfer_kernel< 64, 192, 12, 4, 4><<<dim3(BATCH*64*192*192  / 256), 256, 0, stream>>>(ref1, Rarg, T1_out);
}